// Round 4
// baseline (167.644 us; speedup 1.0000x reference)
//
#include <hip/hip_runtime.h>

constexpr int NN = 10000;
constexpr int NE = 160000;
constexpr int D  = 512;
constexpr int EF = 80;   // RBF(64) + ANG(16)

typedef __attribute__((ext_vector_type(8))) short short8;   // 8 bf16 (4 VGPRs)
typedef __attribute__((ext_vector_type(4))) float f32x4;    // MFMA C/D

static __device__ __forceinline__ ushort f2bf(float f) {
    union { float f; unsigned u; } v; v.f = f;
    unsigned r = (v.u + 0x7FFFu + ((v.u >> 16) & 1u)) >> 16;   // RNE
    return (ushort)r;
}

// ---------------------------------------------------------------------------
// Aggregation via CSR sort (replaces 12.8M f32 atomics with 320K int atomics)
//   K1 hist:      cnt_i[row[e]]++                      (160K int atomics)
//   K2 scan:      off = exclusive_scan(cnt_i)          (1 block, shfl scans)
//   K3 fillsort:  sortedE[off[r] + fill[r]++] = e      (160K int atomics)
//   K4 gather:    aggF[n][f] = sum over node n's edges (exact f32, no atomics)
// ---------------------------------------------------------------------------
__global__ __launch_bounds__(256)
void hist_kernel(const int* __restrict__ row, int* __restrict__ cnt_i) {
    int e = blockIdx.x * 256 + threadIdx.x;
    if (e < NE) atomicAdd(&cnt_i[row[e]], 1);
}

__global__ __launch_bounds__(1024)
void scan_kernel(const int* __restrict__ cnt_i, int* __restrict__ off) {
    __shared__ int wsum[16];
    __shared__ int carry_s;
    const int tid  = threadIdx.x;
    const int lane = tid & 63;
    const int wv   = tid >> 6;
    if (tid == 0) carry_s = 0;
    __syncthreads();
    for (int base = 0; base < NN; base += 1024) {
        const int i = base + tid;
        const int v = (i < NN) ? cnt_i[i] : 0;
        // inclusive scan within wave (shfl, no barriers)
        int s = v;
        #pragma unroll
        for (int d = 1; d < 64; d <<= 1) {
            int t = __shfl_up(s, d, 64);
            if (lane >= d) s += t;
        }
        if (lane == 63) wsum[wv] = s;
        __syncthreads();
        if (wv == 0 && lane < 16) {             // scan the 16 wave sums
            int ws = wsum[lane];
            #pragma unroll
            for (int d = 1; d < 16; d <<= 1) {
                int t = __shfl_up(ws, d, 64);
                if (lane >= d) ws += t;
            }
            wsum[lane] = ws;                    // inclusive
        }
        __syncthreads();
        const int carry = carry_s;
        const int wbase = (wv == 0) ? 0 : wsum[wv - 1];
        if (i < NN) off[i] = carry + wbase + s - v;   // exclusive prefix
        __syncthreads();                         // everyone read carry_s/wsum
        if (tid == 0) carry_s = carry + wsum[15];
        __syncthreads();
    }
    if (threadIdx.x == 0) off[NN] = carry_s;
}

__global__ __launch_bounds__(256)
void fillsort_kernel(const int* __restrict__ row, const int* __restrict__ off,
                     int* __restrict__ fill, int* __restrict__ sortedE) {
    int e = blockIdx.x * 256 + threadIdx.x;
    if (e < NE) {
        int r = row[e];
        int p = off[r] + atomicAdd(&fill[r], 1);
        sortedE[p] = e;
    }
}

__global__ __launch_bounds__(256)
void gather_agg_kernel(const int* __restrict__ off,
                       const int* __restrict__ sortedE,
                       const float* __restrict__ rbf,
                       const float* __restrict__ ang,
                       float* __restrict__ aggF,
                       float* __restrict__ cntf) {
    const int nl = threadIdx.x / 80;        // 0..2 (tid>=240 idle)
    const int f  = threadIdx.x - nl * 80;
    const int n  = blockIdx.x * 3 + nl;
    if (nl >= 3 || n >= NN) return;
    const int i0 = off[n], i1 = off[n + 1];
    float s = 0.f;
    for (int i = i0; i < i1; ++i) {
        const int e = sortedE[i];
        s += (f < 64) ? rbf[e * 64 + f] : ang[e * 16 + (f - 64)];
    }
    aggF[n * EF + f] = s;
    if (f == 0) cntf[n] = (float)(i1 - i0);
}

// ---------------------------------------------------------------------------
// Edge GEMM (fp32, K=80): agg_bf16[M,512] = bf16(aggF @ W_edge + cnt*b_edge)
// segment_sum(edge@W+b) == segment_sum(edge)@W + cnt*b
// ---------------------------------------------------------------------------
__global__ __launch_bounds__(256)
void edge_gemm_kernel(const float* __restrict__ A,     // aggF [M][80]
                      const float* __restrict__ B,     // W_edge [80][512]
                      const float* __restrict__ bias,  // b_edge [512]
                      const float* __restrict__ cnt,   // [M]
                      ushort* __restrict__ C, int M) {
    __shared__ float As[16][64];
    __shared__ float Bs[16][64];
    const int tid = threadIdx.x;
    const int tx = tid & 15;
    const int ty = tid >> 4;
    const int n0 = blockIdx.x * 64;
    const int m0 = blockIdx.y * 64;

    float acc[4][4] = {};
    const int am  = tid >> 2;
    const int akg = tid & 3;
    const int bk  = tid >> 4;
    const int bg  = tid & 15;

    for (int k0 = 0; k0 < EF; k0 += 16) {
        float4 av;
        if (m0 + am < M) {
            av = *reinterpret_cast<const float4*>(&A[(long long)(m0 + am) * EF + k0 + akg * 4]);
        } else {
            av = make_float4(0.f, 0.f, 0.f, 0.f);
        }
        float4 bv = *reinterpret_cast<const float4*>(&B[(long long)(k0 + bk) * D + n0 + bg * 4]);
        __syncthreads();
        As[akg * 4 + 0][am] = av.x;
        As[akg * 4 + 1][am] = av.y;
        As[akg * 4 + 2][am] = av.z;
        As[akg * 4 + 3][am] = av.w;
        *reinterpret_cast<float4*>(&Bs[bk][bg * 4]) = bv;
        __syncthreads();
        #pragma unroll
        for (int k = 0; k < 16; ++k) {
            float4 a = *reinterpret_cast<const float4*>(&As[k][ty * 4]);
            float4 b = *reinterpret_cast<const float4*>(&Bs[k][tx * 4]);
            float ar[4] = {a.x, a.y, a.z, a.w};
            float br[4] = {b.x, b.y, b.z, b.w};
            #pragma unroll
            for (int i = 0; i < 4; ++i)
                #pragma unroll
                for (int j = 0; j < 4; ++j)
                    acc[i][j] = fmaf(ar[i], br[j], acc[i][j]);
        }
    }
    #pragma unroll
    for (int i = 0; i < 4; ++i) {
        int r = m0 + ty * 4 + i;
        if (r >= M) break;
        float cv = cnt[r];
        #pragma unroll
        for (int j = 0; j < 4; ++j) {
            int c = n0 + tx * 4 + j;
            C[(long long)r * D + c] = f2bf(acc[i][j] + cv * bias[c]);
        }
    }
}

// ---------------------------------------------------------------------------
// W [512][512] f32  ->  Wt [n][k] bf16 (transposed)
// ---------------------------------------------------------------------------
__global__ __launch_bounds__(256)
void transpose_bf16_kernel(const float* __restrict__ W, ushort* __restrict__ Wt) {
    __shared__ float tile[32][33];
    const int bx = blockIdx.x * 32;   // col block (n)
    const int by = blockIdx.y * 32;   // row block (k)
    const int tx = threadIdx.x & 31;
    const int ty = threadIdx.x >> 5;  // 0..7
    #pragma unroll
    for (int i = 0; i < 4; ++i)
        tile[ty + 8 * i][tx] = W[(size_t)(by + ty + 8 * i) * D + bx + tx];
    __syncthreads();
    #pragma unroll
    for (int i = 0; i < 4; ++i)
        Wt[(size_t)(bx + ty + 8 * i) * D + by + tx] = f2bf(tile[tx][ty + 8 * i]);
}

// ---------------------------------------------------------------------------
// MFMA bf16 GEMM: C[M,512] = A[M,512] @ Bt^T  (Bt is [n][k] bf16)
//   MODE 1: h1 = bf16(relu(acc + b1))      -> ushort out
//   MODE 2: out = acc + b2 + x             -> float out
// 64x64 tile, BK=64, 4 waves (2x2), each wave 32x32 via 2x2 16x16x32 frags.
// Grid = 8 x 157 = 1256 blocks; XCD-bijective swizzle (1256 % 8 == 0).
// LDS rows padded to 72 bf16 (144B stride -> 2-way bank aliasing, free).
// ---------------------------------------------------------------------------
template <int MODE>
__global__ __launch_bounds__(256)
void mfma_gemm_kernel(const ushort* __restrict__ A,    // [M][512] bf16
                      const ushort* __restrict__ Bt,   // [512][512] bf16, [n][k]
                      const float* __restrict__ bias,  // [512]
                      const float* __restrict__ xres,  // [M][512] (MODE 2)
                      void* __restrict__ Cout, int M) {
    __shared__ ushort As[64 * 72];
    __shared__ ushort Bs[64 * 72];
    const int tid  = threadIdx.x;
    const int lane = tid & 63;
    const int wid  = tid >> 6;
    const int wm   = wid >> 1;        // 0..1
    const int wn   = wid & 1;         // 0..1

    const int l = blockIdx.y * gridDim.x + blockIdx.x;
    const int nwg = gridDim.x * gridDim.y;
    const int cpx = nwg >> 3;
    const int t_ = (l & 7) * cpx + (l >> 3);
    const int n0 = (t_ & 7) * 64;
    const int m0 = (t_ >> 3) * 64;

    f32x4 acc[2][2] = {};

    const int r0 = tid >> 3;          // 0..31 (staging row base)
    const int k8 = tid & 7;           // 16B chunk within 64-elem K row

    uint4 aReg[2], bReg[2];
    constexpr int KTILES = D / 64;

    #pragma unroll
    for (int p = 0; p < 2; ++p) {
        int row = p * 32 + r0;
        int gm = m0 + row;
        aReg[p] = (gm < M)
            ? reinterpret_cast<const uint4*>(A + (size_t)gm * D)[k8]
            : make_uint4(0u, 0u, 0u, 0u);
        bReg[p] = reinterpret_cast<const uint4*>(Bt + (size_t)(n0 + row) * D)[k8];
    }

    for (int t = 0; t < KTILES; ++t) {
        #pragma unroll
        for (int p = 0; p < 2; ++p) {
            int row = p * 32 + r0;
            *reinterpret_cast<uint4*>(&As[row * 72 + k8 * 8]) = aReg[p];
            *reinterpret_cast<uint4*>(&Bs[row * 72 + k8 * 8]) = bReg[p];
        }
        __syncthreads();
        if (t + 1 < KTILES) {
            const int k0 = (t + 1) * 64;
            #pragma unroll
            for (int p = 0; p < 2; ++p) {
                int row = p * 32 + r0;
                int gm = m0 + row;
                aReg[p] = (gm < M)
                    ? reinterpret_cast<const uint4*>(A + (size_t)gm * D + k0)[k8]
                    : make_uint4(0u, 0u, 0u, 0u);
                bReg[p] = reinterpret_cast<const uint4*>(Bt + (size_t)(n0 + row) * D + k0)[k8];
            }
        }
        #pragma unroll
        for (int kk = 0; kk < 2; ++kk) {
            short8 af[2], bfr[2];
            const int klo = kk * 32 + (lane >> 4) * 8;
            #pragma unroll
            for (int mf = 0; mf < 2; ++mf) {
                int arow = wm * 32 + mf * 16 + (lane & 15);
                af[mf] = *reinterpret_cast<const short8*>(&As[arow * 72 + klo]);
            }
            #pragma unroll
            for (int nf = 0; nf < 2; ++nf) {
                int brow = wn * 32 + nf * 16 + (lane & 15);
                bfr[nf] = *reinterpret_cast<const short8*>(&Bs[brow * 72 + klo]);
            }
            #pragma unroll
            for (int mf = 0; mf < 2; ++mf)
                #pragma unroll
                for (int nf = 0; nf < 2; ++nf)
                    acc[mf][nf] = __builtin_amdgcn_mfma_f32_16x16x32_bf16(
                        af[mf], bfr[nf], acc[mf][nf], 0, 0, 0);
        }
        __syncthreads();
    }

    // epilogue: C/D layout col = lane&15, row = (lane>>4)*4 + reg  [m89]
    float*  outf = (float*)Cout;
    ushort* outh = (ushort*)Cout;
    #pragma unroll
    for (int mf = 0; mf < 2; ++mf) {
        const int rowb = m0 + wm * 32 + mf * 16 + ((lane >> 4) << 2);
        #pragma unroll
        for (int nf = 0; nf < 2; ++nf) {
            const int col = n0 + wn * 32 + nf * 16 + (lane & 15);
            const float bv = bias[col];
            #pragma unroll
            for (int r = 0; r < 4; ++r) {
                const int row = rowb + r;
                if (row < M) {
                    float v = acc[mf][nf][r] + bv;
                    if (MODE == 1) {
                        outh[(size_t)row * D + col] = f2bf(fmaxf(v, 0.f));
                    } else {
                        outf[(size_t)row * D + col] = v + xres[(size_t)row * D + col];
                    }
                }
            }
        }
    }
}

extern "C" void kernel_launch(void* const* d_in, const int* in_sizes, int n_in,
                              void* d_out, int out_size, void* d_ws, size_t ws_size,
                              hipStream_t stream) {
    const float* x      = (const float*)d_in[0];
    const int*   edge_index = (const int*)d_in[2];
    const float* rbf    = (const float*)d_in[3];
    const float* ang    = (const float*)d_in[4];
    const float* W_edge = (const float*)d_in[5];
    const float* b_edge = (const float*)d_in[6];
    const float* W1     = (const float*)d_in[7];
    const float* b1     = (const float*)d_in[8];
    const float* W2     = (const float*)d_in[9];
    const float* b2     = (const float*)d_in[10];
    float* out = (float*)d_out;

    char* w = (char*)d_ws;
    float*  aggF = (float*)w;                        //  3,200,000 B
    float*  cntf = (float*)(w + 3200000);            //     40,000 B
    ushort* agg  = (ushort*)(w + 3240000);           // 10,240,000 B (bf16)
    ushort* h1   = (ushort*)(w + 13480000);          // 10,240,000 B (bf16)
    ushort* W1t  = (ushort*)(w + 23720000);          //    524,288 B
    ushort* W2t  = (ushort*)(w + 24244288);          //    524,288 B

    // CSR scratch aliases the h1 region (dead until mfma_gemm<1> writes it,
    // long after gather_agg consumed the scratch).
    int* cnt_i   = (int*)(w + 13480000);             // 40,000 B
    int* fill    = (int*)(w + 13520000);             // 40,000 B
    int* off     = (int*)(w + 13560000);             // 40,004 B
    int* sortedE = (int*)(w + 13600008);             // 640,000 B

    hipMemsetAsync(w + 13480000, 0, 80000, stream);  // cnt_i + fill

    dim3 tgrid(D / 32, D / 32);
    transpose_bf16_kernel<<<tgrid, 256, 0, stream>>>(W1, W1t);
    transpose_bf16_kernel<<<tgrid, 256, 0, stream>>>(W2, W2t);

    hist_kernel<<<(NE + 255) / 256, 256, 0, stream>>>(edge_index, cnt_i);
    scan_kernel<<<1, 1024, 0, stream>>>(cnt_i, off);
    fillsort_kernel<<<(NE + 255) / 256, 256, 0, stream>>>(edge_index, off, fill, sortedE);
    gather_agg_kernel<<<(NN + 2) / 3, 256, 0, stream>>>(off, sortedE, rbf, ang, aggF, cntf);

    dim3 egrid(D / 64, (NN + 63) / 64);
    edge_gemm_kernel<<<egrid, 256, 0, stream>>>(aggF, W_edge, b_edge, cntf, agg, NN);

    dim3 ggrid(D / 64, (NN + 63) / 64);   // 8 x 157 = 1256 blocks
    mfma_gemm_kernel<1><<<ggrid, 256, 0, stream>>>(agg, W1t, b1, nullptr, h1, NN);
    mfma_gemm_kernel<2><<<ggrid, 256, 0, stream>>>(h1, W2t, b2, x, out, NN);
}

// Round 5
// 134.354 us; speedup vs baseline: 1.2478x; 1.2478x over previous
//
#include <hip/hip_runtime.h>

constexpr int NN = 10000;
constexpr int NE = 160000;
constexpr int D  = 512;
constexpr int EF = 80;   // RBF(64) + ANG(16)

typedef __attribute__((ext_vector_type(8))) short short8;   // 8 bf16 (4 VGPRs)
typedef __attribute__((ext_vector_type(4))) float f32x4;    // MFMA C/D

static __device__ __forceinline__ ushort f2bf(float f) {
    union { float f; unsigned u; } v; v.f = f;
    unsigned r = (v.u + 0x7FFFu + ((v.u >> 16) & 1u)) >> 16;   // RNE
    return (ushort)r;
}

// async global->LDS, 16B per lane; LDS dest = wave-uniform base + lane*16
typedef __attribute__((address_space(3))) unsigned int lds_uint;
typedef const __attribute__((address_space(1))) unsigned int glb_uint;
static __device__ __forceinline__ void gload16(const ushort* g, ushort* l) {
    __builtin_amdgcn_global_load_lds((glb_uint*)g, (lds_uint*)l, 16, 0, 0);
}

// ---------------------------------------------------------------------------
// Aggregation via CSR sort:
//   K1 hist, K2 scan (1 block), K3 fillsort, K4 gather (wave-per-node)
// ---------------------------------------------------------------------------
__global__ __launch_bounds__(256)
void hist_kernel(const int* __restrict__ row, int* __restrict__ cnt_i) {
    int e = blockIdx.x * 256 + threadIdx.x;
    if (e < NE) atomicAdd(&cnt_i[row[e]], 1);
}

__global__ __launch_bounds__(1024)
void scan_kernel(const int* __restrict__ cnt_i, int* __restrict__ off) {
    __shared__ int wsum[16];
    __shared__ int carry_s;
    const int tid  = threadIdx.x;
    const int lane = tid & 63;
    const int wv   = tid >> 6;
    if (tid == 0) carry_s = 0;
    __syncthreads();
    for (int base = 0; base < NN; base += 1024) {
        const int i = base + tid;
        const int v = (i < NN) ? cnt_i[i] : 0;
        int s = v;
        #pragma unroll
        for (int d = 1; d < 64; d <<= 1) {
            int t = __shfl_up(s, d, 64);
            if (lane >= d) s += t;
        }
        if (lane == 63) wsum[wv] = s;
        __syncthreads();
        if (wv == 0 && lane < 16) {
            int ws = wsum[lane];
            #pragma unroll
            for (int d = 1; d < 16; d <<= 1) {
                int t = __shfl_up(ws, d, 64);
                if (lane >= d) ws += t;
            }
            wsum[lane] = ws;
        }
        __syncthreads();
        const int carry = carry_s;
        const int wbase = (wv == 0) ? 0 : wsum[wv - 1];
        if (i < NN) off[i] = carry + wbase + s - v;
        __syncthreads();
        if (tid == 0) carry_s = carry + wsum[15];
        __syncthreads();
    }
    if (threadIdx.x == 0) off[NN] = carry_s;
}

__global__ __launch_bounds__(256)
void fillsort_kernel(const int* __restrict__ row, const int* __restrict__ off,
                     int* __restrict__ fill, int* __restrict__ sortedE) {
    int e = blockIdx.x * 256 + threadIdx.x;
    if (e < NE) {
        int r = row[e];
        int p = off[r] + atomicAdd(&fill[r], 1);
        sortedE[p] = e;
    }
}

// one wave per node: lane = rbf feature; lanes 0-15 also handle ang features.
// 4-edge unroll => ~8 independent loads in flight per iteration.
__global__ __launch_bounds__(256)
void gather_agg_kernel(const int* __restrict__ off,
                       const int* __restrict__ sortedE,
                       const float* __restrict__ rbf,
                       const float* __restrict__ ang,
                       float* __restrict__ aggF,
                       float* __restrict__ cntf) {
    const int wv   = threadIdx.x >> 6;
    const int lane = threadIdx.x & 63;
    const int n    = blockIdx.x * 4 + wv;
    if (n >= NN) return;
    const int i0 = off[n], i1 = off[n + 1];
    float s1 = 0.f, s2 = 0.f;
    int i = i0;
    for (; i + 4 <= i1; i += 4) {
        const int e0 = sortedE[i], e1 = sortedE[i + 1];
        const int e2 = sortedE[i + 2], e3 = sortedE[i + 3];
        const float v0 = rbf[e0 * 64 + lane];
        const float v1 = rbf[e1 * 64 + lane];
        const float v2 = rbf[e2 * 64 + lane];
        const float v3 = rbf[e3 * 64 + lane];
        if (lane < 16) {
            s2 += ang[e0 * 16 + lane] + ang[e1 * 16 + lane]
                + ang[e2 * 16 + lane] + ang[e3 * 16 + lane];
        }
        s1 += v0 + v1 + v2 + v3;
    }
    for (; i < i1; ++i) {
        const int e = sortedE[i];
        s1 += rbf[e * 64 + lane];
        if (lane < 16) s2 += ang[e * 16 + lane];
    }
    aggF[n * EF + lane] = s1;
    if (lane < 16) aggF[n * EF + 64 + lane] = s2;
    if (lane == 0) cntf[n] = (float)(i1 - i0);
}

// ---------------------------------------------------------------------------
// Edge GEMM (fp32, K=80): agg_bf16[M,512] = bf16(aggF @ W_edge + cnt*b_edge)
// segment_sum(edge@W+b) == segment_sum(edge)@W + cnt*b
// ---------------------------------------------------------------------------
__global__ __launch_bounds__(256)
void edge_gemm_kernel(const float* __restrict__ A,
                      const float* __restrict__ B,
                      const float* __restrict__ bias,
                      const float* __restrict__ cnt,
                      ushort* __restrict__ C, int M) {
    __shared__ float As[16][64];
    __shared__ float Bs[16][64];
    const int tid = threadIdx.x;
    const int tx = tid & 15;
    const int ty = tid >> 4;
    const int n0 = blockIdx.x * 64;
    const int m0 = blockIdx.y * 64;

    float acc[4][4] = {};
    const int am  = tid >> 2;
    const int akg = tid & 3;
    const int bk  = tid >> 4;
    const int bg  = tid & 15;

    for (int k0 = 0; k0 < EF; k0 += 16) {
        float4 av;
        if (m0 + am < M) {
            av = *reinterpret_cast<const float4*>(&A[(long long)(m0 + am) * EF + k0 + akg * 4]);
        } else {
            av = make_float4(0.f, 0.f, 0.f, 0.f);
        }
        float4 bv = *reinterpret_cast<const float4*>(&B[(long long)(k0 + bk) * D + n0 + bg * 4]);
        __syncthreads();
        As[akg * 4 + 0][am] = av.x;
        As[akg * 4 + 1][am] = av.y;
        As[akg * 4 + 2][am] = av.z;
        As[akg * 4 + 3][am] = av.w;
        *reinterpret_cast<float4*>(&Bs[bk][bg * 4]) = bv;
        __syncthreads();
        #pragma unroll
        for (int k = 0; k < 16; ++k) {
            float4 a = *reinterpret_cast<const float4*>(&As[k][ty * 4]);
            float4 b = *reinterpret_cast<const float4*>(&Bs[k][tx * 4]);
            float ar[4] = {a.x, a.y, a.z, a.w};
            float br[4] = {b.x, b.y, b.z, b.w};
            #pragma unroll
            for (int i = 0; i < 4; ++i)
                #pragma unroll
                for (int j = 0; j < 4; ++j)
                    acc[i][j] = fmaf(ar[i], br[j], acc[i][j]);
        }
    }
    #pragma unroll
    for (int i = 0; i < 4; ++i) {
        int r = m0 + ty * 4 + i;
        if (r >= M) break;
        float cv = cnt[r];
        #pragma unroll
        for (int j = 0; j < 4; ++j) {
            int c = n0 + tx * 4 + j;
            C[(long long)r * D + c] = f2bf(acc[i][j] + cv * bias[c]);
        }
    }
}

// ---------------------------------------------------------------------------
// W [512][512] f32  ->  Wt [n][k] bf16 (transposed)
// ---------------------------------------------------------------------------
__global__ __launch_bounds__(256)
void transpose_bf16_kernel(const float* __restrict__ W, ushort* __restrict__ Wt) {
    __shared__ float tile[32][33];
    const int bx = blockIdx.x * 32;
    const int by = blockIdx.y * 32;
    const int tx = threadIdx.x & 31;
    const int ty = threadIdx.x >> 5;
    #pragma unroll
    for (int i = 0; i < 4; ++i)
        tile[ty + 8 * i][tx] = W[(size_t)(by + ty + 8 * i) * D + bx + tx];
    __syncthreads();
    #pragma unroll
    for (int i = 0; i < 4; ++i)
        Wt[(size_t)(bx + ty + 8 * i) * D + by + tx] = f2bf(tile[tx][ty + 8 * i]);
}

// ---------------------------------------------------------------------------
// MFMA bf16 GEMM: C[M,512] = A[M,512] @ Bt^T  (Bt is [n][k] bf16)
//   MODE 1: h1 = bf16(relu(acc + b1))      -> ushort out
//   MODE 2: out = acc + b2 + x             -> float out
// 64x64 tile, BK=64, 4 waves (2x2). Staging via global_load_lds(16B) into
// LINEAR LDS [64][64] bf16; bank conflicts fixed by rule #21: XOR-swizzle
// the 16B-chunk index on BOTH the global SOURCE address and the ds_read
// address (chunk ^= row&7) -> frag reads are 2-way (free).
// 2-phase pipeline: issue next-tile stage, compute current, one barrier.
// LDS 2*(8K+8K)=32KB -> 5 blocks/CU. Grid 1256, XCD-bijective swizzle.
// ---------------------------------------------------------------------------
template <int MODE>
__global__ __launch_bounds__(256)
void mfma_gemm_kernel(const ushort* __restrict__ A,    // [M][512] bf16
                      const ushort* __restrict__ Bt,   // [512][512] bf16, [n][k]
                      const float* __restrict__ bias,  // [512]
                      const float* __restrict__ xres,  // [M][512] (MODE 2)
                      void* __restrict__ Cout, int M) {
    __shared__ ushort As[2][64 * 64];
    __shared__ ushort Bs[2][64 * 64];
    const int tid  = threadIdx.x;
    const int lane = tid & 63;
    const int wid  = tid >> 6;
    const int wm   = wid >> 1;        // 0..1
    const int wn   = wid & 1;         // 0..1

    const int l = blockIdx.y * gridDim.x + blockIdx.x;
    const int cpx = (gridDim.x * gridDim.y) >> 3;
    const int t_ = (l & 7) * cpx + (l >> 3);
    const int n0 = (t_ & 7) * 64;
    const int m0 = (t_ >> 3) * 64;

    // staging geometry: wave wid loads rows wid*16 + j*8 + (lane>>3),
    // 16B chunk (lane&7); global chunk pre-swizzled by ^(row&7).
    const int sr = lane >> 3;         // 0..7
    const int sc = lane & 7;          // 0..7

    f32x4 acc[2][2] = {};
    constexpr int KTILES = D / 64;

    auto stage = [&](int buf, int t) {
        #pragma unroll
        for (int j = 0; j < 2; ++j) {
            const int r  = wid * 16 + j * 8 + sr;
            const int cs = (sc ^ (r & 7)) * 8;            // swizzled src chunk
            const int rowbase = wid * 16 + j * 8;          // wave-uniform
            gload16(A  + (size_t)(m0 + r) * D + t * 64 + cs, &As[buf][rowbase * 64]);
            gload16(Bt + (size_t)(n0 + r) * D + t * 64 + cs, &Bs[buf][rowbase * 64]);
        }
    };

    stage(0, 0);
    __syncthreads();

    for (int t = 0; t < KTILES; ++t) {
        const int cur = t & 1;
        if (t + 1 < KTILES) stage(cur ^ 1, t + 1);
        #pragma unroll
        for (int kk = 0; kk < 2; ++kk) {
            const int kc = kk * 4 + (lane >> 4);          // 16B chunk in K
            short8 af[2], bfr[2];
            #pragma unroll
            for (int mf = 0; mf < 2; ++mf) {
                const int ar = wm * 32 + mf * 16 + (lane & 15);
                af[mf] = *reinterpret_cast<const short8*>(
                    &As[cur][ar * 64 + ((kc ^ (ar & 7)) * 8)]);
            }
            #pragma unroll
            for (int nf = 0; nf < 2; ++nf) {
                const int br = wn * 32 + nf * 16 + (lane & 15);
                bfr[nf] = *reinterpret_cast<const short8*>(
                    &Bs[cur][br * 64 + ((kc ^ (br & 7)) * 8)]);
            }
            #pragma unroll
            for (int mf = 0; mf < 2; ++mf)
                #pragma unroll
                for (int nf = 0; nf < 2; ++nf)
                    acc[mf][nf] = __builtin_amdgcn_mfma_f32_16x16x32_bf16(
                        af[mf], bfr[nf], acc[mf][nf], 0, 0, 0);
        }
        __syncthreads();   // drains vmcnt (stage) + ensures LDS reads done
    }

    // epilogue: C/D layout col = lane&15, row = (lane>>4)*4 + reg  [m89]
    float*  outf = (float*)Cout;
    ushort* outh = (ushort*)Cout;
    #pragma unroll
    for (int mf = 0; mf < 2; ++mf) {
        const int rowb = m0 + wm * 32 + mf * 16 + ((lane >> 4) << 2);
        #pragma unroll
        for (int nf = 0; nf < 2; ++nf) {
            const int col = n0 + wn * 32 + nf * 16 + (lane & 15);
            const float bv = bias[col];
            #pragma unroll
            for (int r = 0; r < 4; ++r) {
                const int row = rowb + r;
                if (row < M) {
                    float v = acc[mf][nf][r] + bv;
                    if (MODE == 1) {
                        outh[(size_t)row * D + col] = f2bf(fmaxf(v, 0.f));
                    } else {
                        outf[(size_t)row * D + col] = v + xres[(size_t)row * D + col];
                    }
                }
            }
        }
    }
}

extern "C" void kernel_launch(void* const* d_in, const int* in_sizes, int n_in,
                              void* d_out, int out_size, void* d_ws, size_t ws_size,
                              hipStream_t stream) {
    const float* x      = (const float*)d_in[0];
    const int*   edge_index = (const int*)d_in[2];
    const float* rbf    = (const float*)d_in[3];
    const float* ang    = (const float*)d_in[4];
    const float* W_edge = (const float*)d_in[5];
    const float* b_edge = (const float*)d_in[6];
    const float* W1     = (const float*)d_in[7];
    const float* b1     = (const float*)d_in[8];
    const float* W2     = (const float*)d_in[9];
    const float* b2     = (const float*)d_in[10];
    float* out = (float*)d_out;

    char* w = (char*)d_ws;
    float*  aggF = (float*)w;                        //  3,200,000 B
    float*  cntf = (float*)(w + 3200000);            //     40,000 B
    ushort* agg  = (ushort*)(w + 3240000);           // 10,240,000 B (bf16)
    ushort* h1   = (ushort*)(w + 13480000);          // 10,240,000 B (bf16)
    ushort* W1t  = (ushort*)(w + 23720000);          //    524,288 B
    ushort* W2t  = (ushort*)(w + 24244288);          //    524,288 B

    // CSR scratch aliases the h1 region (dead until mfma_gemm<1> writes it).
    int* cnt_i   = (int*)(w + 13480000);             // 40,000 B
    int* fill    = (int*)(w + 13520000);             // 40,000 B
    int* off     = (int*)(w + 13560000);             // 40,004 B
    int* sortedE = (int*)(w + 13600008);             // 640,000 B

    hipMemsetAsync(w + 13480000, 0, 80000, stream);  // cnt_i + fill

    dim3 tgrid(D / 32, D / 32);
    transpose_bf16_kernel<<<tgrid, 256, 0, stream>>>(W1, W1t);
    transpose_bf16_kernel<<<tgrid, 256, 0, stream>>>(W2, W2t);

    hist_kernel<<<(NE + 255) / 256, 256, 0, stream>>>(edge_index, cnt_i);
    scan_kernel<<<1, 1024, 0, stream>>>(cnt_i, off);
    fillsort_kernel<<<(NE + 255) / 256, 256, 0, stream>>>(edge_index, off, fill, sortedE);
    gather_agg_kernel<<<(NN + 3) / 4, 256, 0, stream>>>(off, sortedE, rbf, ang, aggF, cntf);

    dim3 egrid(D / 64, (NN + 63) / 64);
    edge_gemm_kernel<<<egrid, 256, 0, stream>>>(aggF, W_edge, b_edge, cntf, agg, NN);

    dim3 ggrid(D / 64, (NN + 63) / 64);   // 8 x 157 = 1256 blocks
    mfma_gemm_kernel<1><<<ggrid, 256, 0, stream>>>(agg, W1t, b1, nullptr, h1, NN);
    mfma_gemm_kernel<2><<<ggrid, 256, 0, stream>>>(h1, W2t, b2, x, out, NN);
}

// Round 6
// 124.056 us; speedup vs baseline: 1.3514x; 1.0830x over previous
//
#include <hip/hip_runtime.h>

constexpr int NN = 10000;
constexpr int NE = 160000;
constexpr int D  = 512;
constexpr int EF = 80;   // RBF(64) + ANG(16)

typedef __attribute__((ext_vector_type(8))) short short8;   // 8 bf16 (4 VGPRs)
typedef __attribute__((ext_vector_type(4))) float f32x4;    // MFMA C/D

static __device__ __forceinline__ ushort f2bf(float f) {
    union { float f; unsigned u; } v; v.f = f;
    unsigned r = (v.u + 0x7FFFu + ((v.u >> 16) & 1u)) >> 16;   // RNE
    return (ushort)r;
}

// async global->LDS, 16B per lane; LDS dest = wave-uniform base + lane*16
typedef __attribute__((address_space(3))) unsigned int lds_uint;
typedef const __attribute__((address_space(1))) unsigned int glb_uint;
static __device__ __forceinline__ void gload16(const ushort* g, ushort* l) {
    __builtin_amdgcn_global_load_lds((glb_uint*)g, (lds_uint*)l, 16, 0, 0);
}

// ---------------------------------------------------------------------------
// zero_kernel: replaces hipMemsetAsync (runtime fill kernel cost 40us for
// 80KB in the timed graph -- R5 counter finding). 40KB in ~1-2us.
// ---------------------------------------------------------------------------
__global__ __launch_bounds__(256)
void zero_kernel(int* __restrict__ p, int n) {
    int i = blockIdx.x * 256 + threadIdx.x;
    if (i < n) p[i] = 0;
}

// ---------------------------------------------------------------------------
// Aggregation via CSR sort:
//   K1 hist, K2 scan (1 block; writes off + cursor), K3 fillsort (cursor),
//   K4 gather (wave-per-node)
// ---------------------------------------------------------------------------
__global__ __launch_bounds__(256)
void hist_kernel(const int* __restrict__ row, int* __restrict__ cnt_i) {
    int e = blockIdx.x * 256 + threadIdx.x;
    if (e < NE) atomicAdd(&cnt_i[row[e]], 1);
}

__global__ __launch_bounds__(1024)
void scan_kernel(const int* __restrict__ cnt_i, int* __restrict__ off,
                 int* __restrict__ cursor) {
    __shared__ int wsum[16];
    __shared__ int carry_s;
    const int tid  = threadIdx.x;
    const int lane = tid & 63;
    const int wv   = tid >> 6;
    if (tid == 0) carry_s = 0;
    __syncthreads();
    for (int base = 0; base < NN; base += 1024) {
        const int i = base + tid;
        const int v = (i < NN) ? cnt_i[i] : 0;
        int s = v;
        #pragma unroll
        for (int d = 1; d < 64; d <<= 1) {
            int t = __shfl_up(s, d, 64);
            if (lane >= d) s += t;
        }
        if (lane == 63) wsum[wv] = s;
        __syncthreads();
        if (wv == 0 && lane < 16) {
            int ws = wsum[lane];
            #pragma unroll
            for (int d = 1; d < 16; d <<= 1) {
                int t = __shfl_up(ws, d, 64);
                if (lane >= d) ws += t;
            }
            wsum[lane] = ws;
        }
        __syncthreads();
        const int carry = carry_s;
        const int wbase = (wv == 0) ? 0 : wsum[wv - 1];
        if (i < NN) {
            const int e = carry + wbase + s - v;   // exclusive prefix
            off[i] = e;
            cursor[i] = e;
        }
        __syncthreads();
        if (tid == 0) carry_s = carry + wsum[15];
        __syncthreads();
    }
    if (threadIdx.x == 0) off[NN] = carry_s;
}

__global__ __launch_bounds__(256)
void fillsort_kernel(const int* __restrict__ row, int* __restrict__ cursor,
                     int* __restrict__ sortedE) {
    int e = blockIdx.x * 256 + threadIdx.x;
    if (e < NE) {
        int p = atomicAdd(&cursor[row[e]], 1);
        sortedE[p] = e;
    }
}

// one wave per node: lane = rbf feature; lanes 0-15 also handle ang features.
// 4-edge unroll => ~8 independent loads in flight per iteration.
__global__ __launch_bounds__(256)
void gather_agg_kernel(const int* __restrict__ off,
                       const int* __restrict__ sortedE,
                       const float* __restrict__ rbf,
                       const float* __restrict__ ang,
                       float* __restrict__ aggF,
                       float* __restrict__ cntf) {
    const int wv   = threadIdx.x >> 6;
    const int lane = threadIdx.x & 63;
    const int n    = blockIdx.x * 4 + wv;
    if (n >= NN) return;
    const int i0 = off[n], i1 = off[n + 1];
    float s1 = 0.f, s2 = 0.f;
    int i = i0;
    for (; i + 4 <= i1; i += 4) {
        const int e0 = sortedE[i], e1 = sortedE[i + 1];
        const int e2 = sortedE[i + 2], e3 = sortedE[i + 3];
        const float v0 = rbf[e0 * 64 + lane];
        const float v1 = rbf[e1 * 64 + lane];
        const float v2 = rbf[e2 * 64 + lane];
        const float v3 = rbf[e3 * 64 + lane];
        if (lane < 16) {
            s2 += ang[e0 * 16 + lane] + ang[e1 * 16 + lane]
                + ang[e2 * 16 + lane] + ang[e3 * 16 + lane];
        }
        s1 += v0 + v1 + v2 + v3;
    }
    for (; i < i1; ++i) {
        const int e = sortedE[i];
        s1 += rbf[e * 64 + lane];
        if (lane < 16) s2 += ang[e * 16 + lane];
    }
    aggF[n * EF + lane] = s1;
    if (lane < 16) aggF[n * EF + 64 + lane] = s2;
    if (lane == 0) cntf[n] = (float)(i1 - i0);
}

// ---------------------------------------------------------------------------
// Edge GEMM (fp32, K=80): agg_bf16[M,512] = bf16(aggF @ W_edge + cnt*b_edge)
// segment_sum(edge@W+b) == segment_sum(edge)@W + cnt*b
// ---------------------------------------------------------------------------
__global__ __launch_bounds__(256)
void edge_gemm_kernel(const float* __restrict__ A,
                      const float* __restrict__ B,
                      const float* __restrict__ bias,
                      const float* __restrict__ cnt,
                      ushort* __restrict__ C, int M) {
    __shared__ float As[16][64];
    __shared__ float Bs[16][64];
    const int tid = threadIdx.x;
    const int tx = tid & 15;
    const int ty = tid >> 4;
    const int n0 = blockIdx.x * 64;
    const int m0 = blockIdx.y * 64;

    float acc[4][4] = {};
    const int am  = tid >> 2;
    const int akg = tid & 3;
    const int bk  = tid >> 4;
    const int bg  = tid & 15;

    for (int k0 = 0; k0 < EF; k0 += 16) {
        float4 av;
        if (m0 + am < M) {
            av = *reinterpret_cast<const float4*>(&A[(long long)(m0 + am) * EF + k0 + akg * 4]);
        } else {
            av = make_float4(0.f, 0.f, 0.f, 0.f);
        }
        float4 bv = *reinterpret_cast<const float4*>(&B[(long long)(k0 + bk) * D + n0 + bg * 4]);
        __syncthreads();
        As[akg * 4 + 0][am] = av.x;
        As[akg * 4 + 1][am] = av.y;
        As[akg * 4 + 2][am] = av.z;
        As[akg * 4 + 3][am] = av.w;
        *reinterpret_cast<float4*>(&Bs[bk][bg * 4]) = bv;
        __syncthreads();
        #pragma unroll
        for (int k = 0; k < 16; ++k) {
            float4 a = *reinterpret_cast<const float4*>(&As[k][ty * 4]);
            float4 b = *reinterpret_cast<const float4*>(&Bs[k][tx * 4]);
            float ar[4] = {a.x, a.y, a.z, a.w};
            float br[4] = {b.x, b.y, b.z, b.w};
            #pragma unroll
            for (int i = 0; i < 4; ++i)
                #pragma unroll
                for (int j = 0; j < 4; ++j)
                    acc[i][j] = fmaf(ar[i], br[j], acc[i][j]);
        }
    }
    #pragma unroll
    for (int i = 0; i < 4; ++i) {
        int r = m0 + ty * 4 + i;
        if (r >= M) break;
        float cv = cnt[r];
        #pragma unroll
        for (int j = 0; j < 4; ++j) {
            int c = n0 + tx * 4 + j;
            C[(long long)r * D + c] = f2bf(acc[i][j] + cv * bias[c]);
        }
    }
}

// ---------------------------------------------------------------------------
// W [512][512] f32  ->  Wt [n][k] bf16 (transposed)
// ---------------------------------------------------------------------------
__global__ __launch_bounds__(256)
void transpose_bf16_kernel(const float* __restrict__ W, ushort* __restrict__ Wt) {
    __shared__ float tile[32][33];
    const int bx = blockIdx.x * 32;
    const int by = blockIdx.y * 32;
    const int tx = threadIdx.x & 31;
    const int ty = threadIdx.x >> 5;
    #pragma unroll
    for (int i = 0; i < 4; ++i)
        tile[ty + 8 * i][tx] = W[(size_t)(by + ty + 8 * i) * D + bx + tx];
    __syncthreads();
    #pragma unroll
    for (int i = 0; i < 4; ++i)
        Wt[(size_t)(bx + ty + 8 * i) * D + by + tx] = f2bf(tile[tx][ty + 8 * i]);
}

// ---------------------------------------------------------------------------
// MFMA bf16 GEMM: C[M,512] = A[M,512] @ Bt^T  (Bt is [n][k] bf16)
//   MODE 1: h1 = bf16(relu(acc + b1))      -> ushort out
//   MODE 2: out = acc + b2 + x             -> float out
// 64x64 tile, BK=64, 4 waves (2x2). global_load_lds(16B) staging, linear
// LDS dest + XOR-swizzled global source + same XOR on ds_read (rule #21).
// 2-phase pipeline, LDS 32KB, grid 1256 XCD-bijective swizzle.
// ---------------------------------------------------------------------------
template <int MODE>
__global__ __launch_bounds__(256)
void mfma_gemm_kernel(const ushort* __restrict__ A,    // [M][512] bf16
                      const ushort* __restrict__ Bt,   // [512][512] bf16, [n][k]
                      const float* __restrict__ bias,  // [512]
                      const float* __restrict__ xres,  // [M][512] (MODE 2)
                      void* __restrict__ Cout, int M) {
    __shared__ ushort As[2][64 * 64];
    __shared__ ushort Bs[2][64 * 64];
    const int tid  = threadIdx.x;
    const int lane = tid & 63;
    const int wid  = tid >> 6;
    const int wm   = wid >> 1;        // 0..1
    const int wn   = wid & 1;         // 0..1

    const int l = blockIdx.y * gridDim.x + blockIdx.x;
    const int cpx = (gridDim.x * gridDim.y) >> 3;
    const int t_ = (l & 7) * cpx + (l >> 3);
    const int n0 = (t_ & 7) * 64;
    const int m0 = (t_ >> 3) * 64;

    const int sr = lane >> 3;         // 0..7
    const int sc = lane & 7;          // 0..7

    f32x4 acc[2][2] = {};
    constexpr int KTILES = D / 64;

    auto stage = [&](int buf, int t) {
        #pragma unroll
        for (int j = 0; j < 2; ++j) {
            const int r  = wid * 16 + j * 8 + sr;
            const int cs = (sc ^ (r & 7)) * 8;            // swizzled src chunk
            const int rowbase = wid * 16 + j * 8;          // wave-uniform
            gload16(A  + (size_t)(m0 + r) * D + t * 64 + cs, &As[buf][rowbase * 64]);
            gload16(Bt + (size_t)(n0 + r) * D + t * 64 + cs, &Bs[buf][rowbase * 64]);
        }
    };

    stage(0, 0);
    __syncthreads();

    for (int t = 0; t < KTILES; ++t) {
        const int cur = t & 1;
        if (t + 1 < KTILES) stage(cur ^ 1, t + 1);
        #pragma unroll
        for (int kk = 0; kk < 2; ++kk) {
            const int kc = kk * 4 + (lane >> 4);          // 16B chunk in K
            short8 af[2], bfr[2];
            #pragma unroll
            for (int mf = 0; mf < 2; ++mf) {
                const int ar = wm * 32 + mf * 16 + (lane & 15);
                af[mf] = *reinterpret_cast<const short8*>(
                    &As[cur][ar * 64 + ((kc ^ (ar & 7)) * 8)]);
            }
            #pragma unroll
            for (int nf = 0; nf < 2; ++nf) {
                const int br = wn * 32 + nf * 16 + (lane & 15);
                bfr[nf] = *reinterpret_cast<const short8*>(
                    &Bs[cur][br * 64 + ((kc ^ (br & 7)) * 8)]);
            }
            #pragma unroll
            for (int mf = 0; mf < 2; ++mf)
                #pragma unroll
                for (int nf = 0; nf < 2; ++nf)
                    acc[mf][nf] = __builtin_amdgcn_mfma_f32_16x16x32_bf16(
                        af[mf], bfr[nf], acc[mf][nf], 0, 0, 0);
        }
        __syncthreads();
    }

    // epilogue: C/D layout col = lane&15, row = (lane>>4)*4 + reg  [m89]
    float*  outf = (float*)Cout;
    ushort* outh = (ushort*)Cout;
    #pragma unroll
    for (int mf = 0; mf < 2; ++mf) {
        const int rowb = m0 + wm * 32 + mf * 16 + ((lane >> 4) << 2);
        #pragma unroll
        for (int nf = 0; nf < 2; ++nf) {
            const int col = n0 + wn * 32 + nf * 16 + (lane & 15);
            const float bv = bias[col];
            #pragma unroll
            for (int r = 0; r < 4; ++r) {
                const int row = rowb + r;
                if (row < M) {
                    float v = acc[mf][nf][r] + bv;
                    if (MODE == 1) {
                        outh[(size_t)row * D + col] = f2bf(fmaxf(v, 0.f));
                    } else {
                        outf[(size_t)row * D + col] = v + xres[(size_t)row * D + col];
                    }
                }
            }
        }
    }
}

extern "C" void kernel_launch(void* const* d_in, const int* in_sizes, int n_in,
                              void* d_out, int out_size, void* d_ws, size_t ws_size,
                              hipStream_t stream) {
    const float* x      = (const float*)d_in[0];
    const int*   edge_index = (const int*)d_in[2];
    const float* rbf    = (const float*)d_in[3];
    const float* ang    = (const float*)d_in[4];
    const float* W_edge = (const float*)d_in[5];
    const float* b_edge = (const float*)d_in[6];
    const float* W1     = (const float*)d_in[7];
    const float* b1     = (const float*)d_in[8];
    const float* W2     = (const float*)d_in[9];
    const float* b2     = (const float*)d_in[10];
    float* out = (float*)d_out;

    char* w = (char*)d_ws;
    float*  aggF = (float*)w;                        //  3,200,000 B
    float*  cntf = (float*)(w + 3200000);            //     40,000 B
    ushort* agg  = (ushort*)(w + 3240000);           // 10,240,000 B (bf16)
    ushort* h1   = (ushort*)(w + 13480000);          // 10,240,000 B (bf16)
    ushort* W1t  = (ushort*)(w + 23720000);          //    524,288 B
    ushort* W2t  = (ushort*)(w + 24244288);          //    524,288 B

    // CSR scratch aliases the h1 region (dead until mfma_gemm<1> writes it).
    int* cnt_i   = (int*)(w + 13480000);             // 40,000 B
    int* off     = (int*)(w + 13520000);             // 40,004 B
    int* cursor  = (int*)(w + 13560008);             // 40,000 B
    int* sortedE = (int*)(w + 13600008);             // 640,000 B

    zero_kernel<<<(NN + 255) / 256, 256, 0, stream>>>(cnt_i, NN);

    dim3 tgrid(D / 32, D / 32);
    transpose_bf16_kernel<<<tgrid, 256, 0, stream>>>(W1, W1t);
    transpose_bf16_kernel<<<tgrid, 256, 0, stream>>>(W2, W2t);

    hist_kernel<<<(NE + 255) / 256, 256, 0, stream>>>(edge_index, cnt_i);
    scan_kernel<<<1, 1024, 0, stream>>>(cnt_i, off, cursor);
    fillsort_kernel<<<(NE + 255) / 256, 256, 0, stream>>>(edge_index, cursor, sortedE);
    gather_agg_kernel<<<(NN + 3) / 4, 256, 0, stream>>>(off, sortedE, rbf, ang, aggF, cntf);

    dim3 egrid(D / 64, (NN + 63) / 64);
    edge_gemm_kernel<<<egrid, 256, 0, stream>>>(aggF, W_edge, b_edge, cntf, agg, NN);

    dim3 ggrid(D / 64, (NN + 63) / 64);   // 8 x 157 = 1256 blocks
    mfma_gemm_kernel<1><<<ggrid, 256, 0, stream>>>(agg, W1t, b1, nullptr, h1, NN);
    mfma_gemm_kernel<2><<<ggrid, 256, 0, stream>>>(h1, W2t, b2, x, out, NN);
}